// Round 8
// baseline (237.009 us; speedup 1.0000x reference)
//
#include <hip/hip_runtime.h>
#include <math.h>

// ---------------------------------------------------------------------------
// Sparse_Attn_Logic — round 8.
// R7: MFMA GEMMs landed (311->234us). branches now top at 54us (VALU 35%,
// occ 18%); ~180us is small-kernel tail + 14 launch gaps. This round:
//  * branches: hoist the channel-independent x-window out of the cc loop
//    (4x fewer LDS window reads), drop in-kernel BN stats (-80 shfl/wave,
//    moved to pstats kernel reading p1/p2), static 2-shfl maxpool,
//    2048 x 256-thread blocks (16 ch/block) for finer residency.
//  * launch surgery: reduce_x merged into prep, bn23_finalize merged into
//    final_ev, 3 transposes merged into 1 kernel: 14 -> 10 dispatches.
// ---------------------------------------------------------------------------

#define L_MP 31

using s8v = __attribute__((ext_vector_type(8))) short;   // 8 bf16 = 4 VGPRs
using f4v = __attribute__((ext_vector_type(4))) float;   // MFMA acc

__device__ __forceinline__ ushort f2bf(float f) {        // RNE fp32->bf16
    unsigned u = __float_as_uint(f);
    u += 0x7fffu + ((u >> 16) & 1u);
    return (ushort)(u >> 16);
}
__device__ __forceinline__ float bf2f(ushort u) {
    return __uint_as_float(((unsigned)u) << 16);
}

// ---------------- K1: x statistics partials (Sx, C[0..15]) ----------------
__global__ __launch_bounds__(256) void xstats_kernel(
    const float* __restrict__ x, double* __restrict__ xp)
{
    __shared__ __align__(16) float xr[1040];
    __shared__ float wred[4][17];
    int b = blockIdx.x, tid = threadIdx.x;
    for (int i = tid; i < 1024; i += 256) xr[i] = x[b * 1024 + i];
    if (tid < 16) xr[1024 + tid] = 0.f;
    __syncthreads();
    float acc[17];
#pragma unroll
    for (int d = 0; d < 17; ++d) acc[d] = 0.f;
    for (int p = tid; p < 1024; p += 256) {
        float v = xr[p];
        acc[16] += v;
#pragma unroll
        for (int d = 0; d < 16; ++d)
            acc[d] += v * xr[p + d];
    }
#pragma unroll
    for (int off = 32; off >= 1; off >>= 1)
#pragma unroll
        for (int d = 0; d < 17; ++d)
            acc[d] += __shfl_down(acc[d], off);
    int wave = tid >> 6, lane = tid & 63;
    if (lane == 0)
        for (int d = 0; d < 17; ++d) wred[wave][d] = acc[d];
    __syncthreads();
    if (tid < 17) {
        double tot = (double)wred[0][tid] + (double)wred[1][tid]
                   + (double)wred[2][tid] + (double)wred[3][tid];
        xp[tid * 1024 + b] = tot;
    }
}

// ---------------- K2: reduce xp + filters + analytic BN1 (merged) ---------
__global__ __launch_bounds__(512) void prep_kernel(
    const double* __restrict__ xp,
    const float* __restrict__ la_a, const float* __restrict__ la_b,
    const float* __restrict__ bn1_g, const float* __restrict__ bn1_b,
    float* __restrict__ g18_out, float* __restrict__ a1d1_out)
{
    __shared__ double stats[17];
    __shared__ float fs[32][16];
    int tid = threadIdx.x, wv = tid >> 6, lane = tid & 63;

    // reduce xp[17][1024] -> stats (wave wv handles rows wv, wv+8, wv+16)
    for (int row = wv; row < 17; row += 8) {
        const double* r = xp + (size_t)row * 1024;
        double a = 0.0;
        for (int i = lane; i < 1024; i += 64) a += r[i];
#pragma unroll
        for (int off = 32; off >= 1; off >>= 1) a += __shfl_down(a, off);
        if (lane == 0) stats[row] = a;
    }

    {
        int c = tid >> 4, k = tid & 15;
        const double A = 0.08, ep = 0.03, tal = 0.1;
        const double w = 2.0 * 3.14159265358979323846 * 50.0;
        const double q = 1.0 - ep * ep;
        double t = (double)k / 15.0;
        double p = t - (double)la_b[c] / (double)la_a[c];
        double arg = w * (p - tal);
        double y = A * exp(-ep / sqrt(q) * arg) * (-sin(arg));
        fs[c][k] = (float)y;
    }
    __syncthreads();
    if (tid < 32) {
        int c = tid;
        for (int i = 0; i < 18; ++i) {
            float g = 0.f;
            for (int k = i - 2; k <= i; ++k)
                if (k >= 0 && k < 16) g += fs[c][k];
            g18_out[c * 18 + i] = g;
        }
        double Sf = 0.0;
        for (int k = 0; k < 16; ++k) Sf += (double)fs[c][k];
        double E2 = 0.0;
        for (int k = 0; k < 16; ++k)
            for (int k2 = 0; k2 < 16; ++k2)
                E2 += (double)fs[c][k] * (double)fs[c][k2]
                    * stats[k > k2 ? k - k2 : k2 - k];
        const double N = 1024.0 * 1041.0;
        double Sx = stats[16];
        double mc  = Sx * Sf / N;
        double var = E2 / N - mc * mc;
        double invstd = 1.0 / sqrt(var + 1e-5);
        float alpha = bn1_g[c] * (float)invstd;
        a1d1_out[c]      = alpha / 3.0f;
        a1d1_out[32 + c] = bn1_b[c] - (float)mc * alpha;
    }
}

// ---------------- K3: fused conv+BN+pool + both branches ------------------
// 2048 blocks x 256 thr; block (b, hf) owns channels hf*16..hf*16+15; wave wv
// handles local channels wv*4+cc. x window hoisted out of the cc loop
// (channel-independent). No stats reduction here (see pstats_kernel).
__global__ __launch_bounds__(256) void branches_kernel(
    const float* __restrict__ x,
    const float* __restrict__ g18g, const float* __restrict__ a1d1,
    const float* __restrict__ a1w_g, const float* __restrict__ a1b_g,
    const float* __restrict__ e1w_g, const float* __restrict__ e1b_g,
    const float* __restrict__ f1w_g, const float* __restrict__ f1b_g,
    const float* __restrict__ faw_g, const float* __restrict__ fab_g,
    float* __restrict__ p1, float* __restrict__ p2)
{
    __shared__ float xs[1140];            // swizzled x, P(i)=i+(i>>4)
    __shared__ float g18s[16][18];
    __shared__ float wts[4][16][8];       // 0=a1w 1=e1w 2=f1w 3=faw (local ch)
    __shared__ float htail[16][6];        // BN-applied h[512+e], local ch

    int blk = blockIdx.x;
    int b = blk >> 1, hf = blk & 1;
    int t = threadIdx.x;
    int wv = t >> 6, lane = t & 63;

    for (int i = t; i < 1072; i += 256) {
        float v = 0.f;
        if (i >= 16 && i < 1040) v = x[(size_t)b * 1024 + (i - 16)];
        xs[i + (i >> 4)] = v;
    }
    if (t < 144) ((float2*)&g18s[0][0])[t] = ((const float2*)(g18g + hf * 288))[t];
    if (t < 128) {
        wts[0][0][t] = a1w_g[hf * 128 + t];
        wts[1][0][t] = e1w_g[hf * 128 + t];
        wts[2][0][t] = f1w_g[hf * 128 + t];
        wts[3][0][t] = faw_g[hf * 128 + t];
    }
    __syncthreads();

    if (t < 96) {
        int cl = t / 6, e = t - 6 * (t / 6);
        int cg = hf * 16 + cl;
        float s = 0.f;
#pragma unroll
        for (int i = 0; i < 18; ++i) {
            int li = 1024 + 2 * e + i;
            s += g18s[cl][i] * xs[li + (li >> 4)];
        }
        htail[cl][e] = s * a1d1[cg] + a1d1[32 + cg];
    }
    __syncthreads();

    // ---- hoisted x window: logical xl[16l..16l+31], conflict-free swizzle
    float xw[32];
    {
        int base = 17 * lane;
#pragma unroll
        for (int q = 0; q < 16; ++q) xw[q] = xs[base + q];
#pragma unroll
        for (int q = 0; q < 16; ++q) xw[16 + q] = xs[base + 17 + q];
    }

    for (int cc = 0; cc < 4; ++cc) {
        int cl = wv * 4 + cc;
        int cg = hf * 16 + cl;
        float alpha = a1d1[cg], delta = a1d1[32 + cg];

        // ---- conv + BN1 + avgpool: h[8l..8l+7] in registers ----
        float hv[8];
        {
            float g[18];
#pragma unroll
            for (int i = 0; i < 18; ++i) g[i] = g18s[cl][i];
#pragma unroll
            for (int jj = 0; jj < 8; ++jj) {
                float s = 0.f;
#pragma unroll
                for (int i = 0; i < 18; ++i) s += g[i] * xw[2 * jj + i];
                hv[jj] = s * alpha + delta;
            }
        }

        // ---- stage 1: x1[4l..4l+3] / x2 (Always a1 / Eventually f1) ------
        float x1v[4], x2v[4];
        {
            float hx[14];
#pragma unroll
            for (int q = 0; q < 8; ++q) hx[q] = hv[q];
#pragma unroll
            for (int q = 0; q < 6; ++q) {
                float u = __shfl_down(hv[q], 1);
                float tl = htail[cl][q];
                hx[8 + q] = (lane == 63) ? tl : u;
            }
            float wa[8], wf[8];
            float A1 = a1b_g[cg], F1 = 1.f - f1b_g[cg];
#pragma unroll
            for (int k = 0; k < 8; ++k) {
                wa[k] = wts[0][cl][k];
                wf[k] = wts[2][cl][k];
                A1 -= wa[k];
            }
#pragma unroll
            for (int nn = 0; nn < 4; ++nn) {
                float s1 = A1, s2 = F1;
#pragma unroll
                for (int k = 0; k < 8; ++k) {
                    float h = hx[2 * nn + k];
                    s1 += h * wa[k];
                    s2 += h * wf[k];
                }
                x1v[nn] = s1 > 0.f ? s1 : 0.f;
                x2v[nn] = s2 > 0.f ? s2 : 0.f;
            }
        }

        // ---- stage 2: y[2l], y[2l+1] (Eventually e1 / Always fa) ---------
        float y1v[2], y2v[2];
        {
            float xx1[10], xx2[10];
#pragma unroll
            for (int q = 0; q < 4; ++q) { xx1[q] = x1v[q]; xx2[q] = x2v[q]; }
#pragma unroll
            for (int q = 0; q < 4; ++q) {
                xx1[4 + q] = __shfl_down(x1v[q], 1);
                xx2[4 + q] = __shfl_down(x2v[q], 1);
            }
#pragma unroll
            for (int q = 0; q < 2; ++q) {
                xx1[8 + q] = __shfl_down(x1v[q], 2);
                xx2[8 + q] = __shfl_down(x2v[q], 2);
            }
            float we[8], wfa[8];
            float E1 = 1.f - e1b_g[cg], FA = fab_g[cg];
#pragma unroll
            for (int k = 0; k < 8; ++k) {
                we[k]  = wts[1][cl][k];
                wfa[k] = wts[3][cl][k];
                FA -= wfa[k];
            }
#pragma unroll
            for (int mm = 0; mm < 2; ++mm) {
                float s1 = E1, s2 = FA;
#pragma unroll
                for (int k = 0; k < 8; ++k) {
                    s1 += xx1[2 * mm + k] * we[k];
                    s2 += xx2[2 * mm + k] * wfa[k];
                }
                y1v[mm] = s1 > 0.f ? s1 : 0.f;
                y2v[mm] = s2 > 0.f ? s2 : 0.f;
            }
        }

        // ---- maxpool(4,4): lane pre-max + one static shfl ----------------
        {
            float m1 = fmaxf(y1v[0], y1v[1]);
            float m2 = fmaxf(y2v[0], y2v[1]);
            float n1 = __shfl_down(m1, 1);
            float n2 = __shfl_down(m2, 1);
            int tt = lane >> 1;
            if (!(lane & 1) && tt < L_MP) {
                int bc = b * 32 + cg;
                p1[(size_t)bc * L_MP + tt] = fmaxf(m1, n1);
                p2[(size_t)bc * L_MP + tt] = fmaxf(m2, n2);
            }
        }
    }
}

// ---------------- K3b: BN2/3 stats from p1/p2 (64 blocks) -----------------
// block (arr, c): sum & sumsq over all (b, t) of p_arr[b][c][t] -> bn_d
// layout: bn_d[arr*64 + c] = sum, bn_d[arr*64 + 32 + c] = sumsq.
__global__ __launch_bounds__(256) void pstats_kernel(
    const float* __restrict__ p1, const float* __restrict__ p2,
    double* __restrict__ bn_d)
{
    __shared__ double wr[4][2];
    int bx = blockIdx.x, arr = bx >> 5, c = bx & 31;
    const float* p = arr ? p2 : p1;
    int t = threadIdx.x, wv = t >> 6, lane = t & 63;
    double s = 0.0, q = 0.0;
    for (int bb = t; bb < 1024; bb += 256) {
        const float* r = p + ((size_t)bb * 32 + c) * L_MP;
#pragma unroll
        for (int j = 0; j < L_MP; ++j) {
            double v = (double)r[j];
            s += v; q += v * v;
        }
    }
#pragma unroll
    for (int off = 32; off >= 1; off >>= 1) {
        s += __shfl_down(s, off);
        q += __shfl_down(q, off);
    }
    if (lane == 0) { wr[wv][0] = s; wr[wv][1] = q; }
    __syncthreads();
    if (t == 0) {
        bn_d[arr * 64 + c]      = wr[0][0] + wr[1][0] + wr[2][0] + wr[3][0];
        bn_d[arr * 64 + 32 + c] = wr[0][1] + wr[1][1] + wr[2][1] + wr[3][1];
    }
}

// ---------------- K5: BN finalize + apply + last Eventually + concat ------
__global__ __launch_bounds__(256) void final_ev_kernel(
    const float* __restrict__ p1, const float* __restrict__ p2,
    const float* __restrict__ e2w_g, const float* __restrict__ e2b_g,
    const float* __restrict__ f2w_g, const float* __restrict__ f2b_g,
    const double* __restrict__ bn_d,
    const float* __restrict__ bn2_g, const float* __restrict__ bn2_b,
    const float* __restrict__ bn3_g, const float* __restrict__ bn3_b,
    ushort* __restrict__ z0)
{
    __shared__ float pr[2][32][31];
    __shared__ float w2s[2][32][8];
    __shared__ float al[2][32], de[2][32], eb[2][32];
    int b = blockIdx.x, tid = threadIdx.x;
    for (int i = tid; i < 992; i += 256) {
        pr[0][0][i] = p1[b * 992 + i];
        pr[1][0][i] = p2[b * 992 + i];
    }
    {
        w2s[0][0][tid] = e2w_g[tid];
        w2s[1][0][tid] = f2w_g[tid];
    }
    if (tid < 64) {       // folded bn23_finalize
        int br = tid >> 5, c = tid & 31;
        double sum = bn_d[br * 64 + c], sq = bn_d[br * 64 + 32 + c];
        const double N = 1024.0 * 31.0;
        double mean = sum / N;
        double var = sq / N - mean * mean;
        float g  = br ? bn3_g[c] : bn2_g[c];
        float be = br ? bn3_b[c] : bn2_b[c];
        float alpha = g * (float)(1.0 / sqrt(var + 1e-5));
        al[br][c] = alpha;
        de[br][c] = be - (float)mean * alpha;
        eb[br][c] = br ? f2b_g[c] : e2b_g[c];
    }
    __syncthreads();
    for (int u = tid; u < 768; u += 256) {
        int br = u / 384, rem = u - br * 384;
        int c = rem / 12, tt = rem - c * 12;
        float a = al[br][c], d = de[br][c];
        float s = 1.f - eb[br][c];
#pragma unroll
        for (int k = 0; k < 8; ++k)
            s += (pr[br][c][2 * tt + k] * a + d) * w2s[br][c][k];
        z0[(size_t)b * 768 + u] = f2bf(s > 0.f ? s : 0.f);
    }
}

// ---------------- merged transpose + fp32->bf16 for all 3 weights ---------
__global__ __launch_bounds__(256) void transpose_all_kernel(
    const float* __restrict__ w1, const float* __restrict__ w2,
    const float* __restrict__ w3,
    ushort* __restrict__ wt1, ushort* __restrict__ wt2, ushort* __restrict__ wt3)
{
    __shared__ float tile[32][33];
    int bx = blockIdx.x;
    const float* W; ushort* Wt; int K, N, ntx, tl;
    if (bx < 768)       { W = w1; Wt = wt1; K = 768;  N = 1024; ntx = 32; tl = bx; }
    else if (bx < 1280) { W = w2; Wt = wt2; K = 1024; N = 512;  ntx = 16; tl = bx - 768; }
    else                { W = w3; Wt = wt3; K = 512;  N = 128;  ntx = 4;  tl = bx - 1280; }
    int n0 = (tl % ntx) * 32, k0 = (tl / ntx) * 32;
    int tx = threadIdx.x & 31, ty = threadIdx.x >> 5;
#pragma unroll
    for (int i = 0; i < 4; ++i)
        tile[ty + 8 * i][tx] = W[(size_t)(k0 + ty + 8 * i) * N + n0 + tx];
    __syncthreads();
#pragma unroll
    for (int i = 0; i < 4; ++i)
        Wt[(size_t)(n0 + ty + 8 * i) * K + k0 + tx] = f2bf(tile[tx][ty + 8 * i]);
}

// ---------------- bf16 MFMA GEMM: C = relu(A @ Bt^T + bias), bf16 out -----
__global__ __launch_bounds__(256) void gemm_mfma_kernel(
    const ushort* __restrict__ A, const ushort* __restrict__ Bt,
    const float* __restrict__ bias, ushort* __restrict__ C,
    int N, int K)
{
    int w = blockIdx.x * 4 + (threadIdx.x >> 6);
    int lane = threadIdx.x & 63;
    int ntiles = N >> 4;
    int mt = w / ntiles, nt = w - mt * ntiles;
    int r = lane & 15, q = lane >> 4;
    const ushort* ap = A + (size_t)(mt * 16 + r) * K + q * 8;
    const ushort* bp = Bt + (size_t)(nt * 16 + r) * K + q * 8;
    f4v acc = {0.f, 0.f, 0.f, 0.f};
    int nk = K >> 5;
    s8v a0 = *(const s8v*)ap;
    s8v b0 = *(const s8v*)bp;
#pragma unroll 4
    for (int i = 0; i < nk; ++i) {
        int j = (i + 1 < nk) ? i + 1 : i;          // depth-1 prefetch
        s8v a1 = *(const s8v*)(ap + (size_t)j * 32);
        s8v b1 = *(const s8v*)(bp + (size_t)j * 32);
        acc = __builtin_amdgcn_mfma_f32_16x16x32_bf16(a0, b0, acc, 0, 0, 0);
        a0 = a1; b0 = b1;
    }
    float bv = bias[nt * 16 + r];
    int row0 = mt * 16 + q * 4;
    int col = nt * 16 + r;
#pragma unroll
    for (int rr = 0; rr < 4; ++rr) {
        float v = acc[rr] + bv;
        v = v > 0.f ? v : 0.f;
        C[(size_t)(row0 + rr) * N + col] = f2bf(v);
    }
}

// ---------------- K9: last FC (N=10), bf16 z3 in, fp32 out ----------------
__global__ __launch_bounds__(256) void fc4_kernel(
    const ushort* __restrict__ z3, const float* __restrict__ w4,
    const float* __restrict__ b4, float* __restrict__ out)
{
    int g = blockIdx.x * 256 + threadIdx.x;
    if (g >= 1024 * 10) return;
    int m = g / 10, n = g - m * 10;
    float acc = b4[n];
#pragma unroll 8
    for (int k = 0; k < 128; ++k)
        acc += bf2f(z3[m * 128 + k]) * w4[k * 10 + n];
    out[g] = acc > 0.f ? acc : 0.f;
}

// ---------------------------------------------------------------------------
extern "C" void kernel_launch(void* const* d_in, const int* in_sizes, int n_in,
                              void* d_out, int out_size, void* d_ws, size_t ws_size,
                              hipStream_t stream)
{
    (void)in_sizes; (void)n_in; (void)out_size; (void)ws_size;
    const float* x      = (const float*)d_in[0];
    const float* la_a   = (const float*)d_in[1];
    const float* la_b   = (const float*)d_in[2];
    const float* bn1_g  = (const float*)d_in[4];
    const float* bn1_b  = (const float*)d_in[5];
    const float* a1_w   = (const float*)d_in[6];
    const float* a1_b   = (const float*)d_in[7];
    const float* e1_w   = (const float*)d_in[8];
    const float* e1_b   = (const float*)d_in[9];
    const float* bn2_g  = (const float*)d_in[10];
    const float* bn2_b  = (const float*)d_in[11];
    const float* e2_w   = (const float*)d_in[12];
    const float* e2_b   = (const float*)d_in[13];
    const float* f1_w   = (const float*)d_in[14];
    const float* f1_b   = (const float*)d_in[15];
    const float* fa_w   = (const float*)d_in[16];
    const float* fa_b   = (const float*)d_in[17];
    const float* bn3_g  = (const float*)d_in[18];
    const float* bn3_b  = (const float*)d_in[19];
    const float* f2_w   = (const float*)d_in[20];
    const float* f2_b   = (const float*)d_in[21];
    const float* w1     = (const float*)d_in[22];
    const float* b1     = (const float*)d_in[23];
    const float* w2     = (const float*)d_in[24];
    const float* b2     = (const float*)d_in[25];
    const float* w3     = (const float*)d_in[26];
    const float* b3     = (const float*)d_in[27];
    const float* w4     = (const float*)d_in[28];
    const float* b4     = (const float*)d_in[29];
    float* out = (float*)d_out;

    char* w = (char*)d_ws;
    double* bn_d    = (double*)(w + 256);      // 128 dbl
    float* g18      = (float*)(w + 1536);
    float* a1d1     = (float*)(w + 3840);
    float* p1       = (float*)(w + 8192);                 // 4,063,232
    float* p2       = (float*)(w + 4071424);              // 4,063,232
    ushort* z0bf    = (ushort*)(w + 8134656);             // 1,572,864
    ushort* z1bf    = (ushort*)(w + 9707520);             // 2,097,152
    ushort* z2bf    = (ushort*)(w + 11804672);            // 1,048,576
    ushort* z3bf    = (ushort*)(w + 12853248);            // 262,144
    ushort* wt1     = (ushort*)(w + 13115392);            // 1,572,864
    ushort* wt2     = (ushort*)(w + 14688256);            // 1,048,576
    ushort* wt3     = (ushort*)(w + 15736832);            // 131,072
    double* xp      = (double*)(w + 15867904);            // 139,264 -> 16,007,168

    xstats_kernel<<<1024, 256, 0, stream>>>(x, xp);
    prep_kernel<<<1, 512, 0, stream>>>(xp, la_a, la_b, bn1_g, bn1_b, g18, a1d1);
    branches_kernel<<<2048, 256, 0, stream>>>(
        x, g18, a1d1, a1_w, a1_b, e1_w, e1_b, f1_w, f1_b, fa_w, fa_b, p1, p2);
    pstats_kernel<<<64, 256, 0, stream>>>(p1, p2, bn_d);
    final_ev_kernel<<<1024, 256, 0, stream>>>(
        p1, p2, e2_w, e2_b, f2_w, f2_b, bn_d, bn2_g, bn2_b, bn3_g, bn3_b, z0bf);
    transpose_all_kernel<<<1344, 256, 0, stream>>>(w1, w2, w3, wt1, wt2, wt3);
    gemm_mfma_kernel<<<1024, 256, 0, stream>>>(z0bf, wt1, b1, z1bf, 1024, 768);
    gemm_mfma_kernel<<<512, 256, 0, stream>>>(z1bf, wt2, b2, z2bf, 512, 1024);
    gemm_mfma_kernel<<<128, 256, 0, stream>>>(z2bf, wt3, b3, z3bf, 128, 512);
    fc4_kernel<<<40, 256, 0, stream>>>(z3bf, w4, b4, out);
}

// Round 9
// 222.630 us; speedup vs baseline: 1.0646x; 1.0646x over previous
//
#include <hip/hip_runtime.h>
#include <math.h>

// ---------------------------------------------------------------------------
// Sparse_Attn_Logic — round 9.
// R8: profile top-5 is now the harness's 268MB ws re-poison fill (~42us,
// uncontrollable); all our kernels are <42us. branches' DS pipe carried ~50
// wave-uniform weight ds_reads per channel (balanced vs VALU -> both ~50%).
// This round: weights via readfirstlane-uniform GLOBAL reads (scalar loads,
// constant cache) — no weight LDS, one less barrier; float4 x staging;
// gemm1/2 pair 2 N-tiles per wave (1.5 loads/MFMA, 2x MFMA ILP).
// ---------------------------------------------------------------------------

#define L_MP 31

using s8v = __attribute__((ext_vector_type(8))) short;   // 8 bf16 = 4 VGPRs
using f4v = __attribute__((ext_vector_type(4))) float;   // MFMA acc

__device__ __forceinline__ ushort f2bf(float f) {        // RNE fp32->bf16
    unsigned u = __float_as_uint(f);
    u += 0x7fffu + ((u >> 16) & 1u);
    return (ushort)(u >> 16);
}
__device__ __forceinline__ float bf2f(ushort u) {
    return __uint_as_float(((unsigned)u) << 16);
}

// ---------------- K1: x statistics partials (Sx, C[0..15]) ----------------
__global__ __launch_bounds__(256) void xstats_kernel(
    const float* __restrict__ x, double* __restrict__ xp)
{
    __shared__ __align__(16) float xr[1040];
    __shared__ float wred[4][17];
    int b = blockIdx.x, tid = threadIdx.x;
    for (int i = tid; i < 1024; i += 256) xr[i] = x[b * 1024 + i];
    if (tid < 16) xr[1024 + tid] = 0.f;
    __syncthreads();
    float acc[17];
#pragma unroll
    for (int d = 0; d < 17; ++d) acc[d] = 0.f;
    for (int p = tid; p < 1024; p += 256) {
        float v = xr[p];
        acc[16] += v;
#pragma unroll
        for (int d = 0; d < 16; ++d)
            acc[d] += v * xr[p + d];
    }
#pragma unroll
    for (int off = 32; off >= 1; off >>= 1)
#pragma unroll
        for (int d = 0; d < 17; ++d)
            acc[d] += __shfl_down(acc[d], off);
    int wave = tid >> 6, lane = tid & 63;
    if (lane == 0)
        for (int d = 0; d < 17; ++d) wred[wave][d] = acc[d];
    __syncthreads();
    if (tid < 17) {
        double tot = (double)wred[0][tid] + (double)wred[1][tid]
                   + (double)wred[2][tid] + (double)wred[3][tid];
        xp[tid * 1024 + b] = tot;
    }
}

// ---------------- K2: reduce xp + filters + analytic BN1 (merged) ---------
__global__ __launch_bounds__(512) void prep_kernel(
    const double* __restrict__ xp,
    const float* __restrict__ la_a, const float* __restrict__ la_b,
    const float* __restrict__ bn1_g, const float* __restrict__ bn1_b,
    float* __restrict__ g18_out, float* __restrict__ a1d1_out)
{
    __shared__ double stats[17];
    __shared__ float fs[32][16];
    int tid = threadIdx.x, wv = tid >> 6, lane = tid & 63;

    for (int row = wv; row < 17; row += 8) {
        const double* r = xp + (size_t)row * 1024;
        double a = 0.0;
        for (int i = lane; i < 1024; i += 64) a += r[i];
#pragma unroll
        for (int off = 32; off >= 1; off >>= 1) a += __shfl_down(a, off);
        if (lane == 0) stats[row] = a;
    }

    {
        int c = tid >> 4, k = tid & 15;
        const double A = 0.08, ep = 0.03, tal = 0.1;
        const double w = 2.0 * 3.14159265358979323846 * 50.0;
        const double q = 1.0 - ep * ep;
        double t = (double)k / 15.0;
        double p = t - (double)la_b[c] / (double)la_a[c];
        double arg = w * (p - tal);
        double y = A * exp(-ep / sqrt(q) * arg) * (-sin(arg));
        fs[c][k] = (float)y;
    }
    __syncthreads();
    if (tid < 32) {
        int c = tid;
        for (int i = 0; i < 18; ++i) {
            float g = 0.f;
            for (int k = i - 2; k <= i; ++k)
                if (k >= 0 && k < 16) g += fs[c][k];
            g18_out[c * 18 + i] = g;
        }
        double Sf = 0.0;
        for (int k = 0; k < 16; ++k) Sf += (double)fs[c][k];
        double E2 = 0.0;
        for (int k = 0; k < 16; ++k)
            for (int k2 = 0; k2 < 16; ++k2)
                E2 += (double)fs[c][k] * (double)fs[c][k2]
                    * stats[k > k2 ? k - k2 : k2 - k];
        const double N = 1024.0 * 1041.0;
        double Sx = stats[16];
        double mc  = Sx * Sf / N;
        double var = E2 / N - mc * mc;
        double invstd = 1.0 / sqrt(var + 1e-5);
        float alpha = bn1_g[c] * (float)invstd;
        a1d1_out[c]      = alpha / 3.0f;
        a1d1_out[32 + c] = bn1_b[c] - (float)mc * alpha;
    }
}

// ---------------- K3: fused conv+BN+pool + both branches ------------------
// 2048 blocks x 256 thr; block (b,hf) owns channels hf*16..+15; wave wv does
// local channels wv*4+cc. All per-channel weights/biases read with a
// readfirstlane-uniform index from const __restrict global -> scalar loads
// (constant cache), keeping the DS pipe for the x window + shuffles only.
__global__ __launch_bounds__(256) void branches_kernel(
    const float* __restrict__ x,
    const float* __restrict__ g18g, const float* __restrict__ a1d1,
    const float* __restrict__ a1w_g, const float* __restrict__ a1b_g,
    const float* __restrict__ e1w_g, const float* __restrict__ e1b_g,
    const float* __restrict__ f1w_g, const float* __restrict__ f1b_g,
    const float* __restrict__ faw_g, const float* __restrict__ fab_g,
    float* __restrict__ p1, float* __restrict__ p2)
{
    __shared__ float xs[1140];            // swizzled x, P(i)=i+(i>>4)
    __shared__ float htail[16][6];        // BN-applied h[512+e], local ch

    int blk = blockIdx.x;
    int b = blk >> 1, hf = blk & 1;
    int t = threadIdx.x;
    int wv = t >> 6, lane = t & 63;

    // ---- stage swizzled x: float4 loads; groups of 4 never cross the
    //      16-boundary, so each maps to 4 consecutive physical slots ----
    {
        float4 v = ((const float4*)(x + (size_t)b * 1024))[t];
        int li = 16 + 4 * t;
        int ph = li + (li >> 4);
        xs[ph] = v.x; xs[ph + 1] = v.y; xs[ph + 2] = v.z; xs[ph + 3] = v.w;
        if (t < 16) xs[t] = 0.f;                       // P(i)=i for i<16
        if (t < 32) { int i = 1040 + t; xs[i + (i >> 4)] = 0.f; }
    }
    __syncthreads();

    // ---- precompute channel tails h[512..517] (per-thread vector loads) --
    if (t < 96) {
        int cl = t / 6, e = t - 6 * (t / 6);
        int cg = hf * 16 + cl;
        float s = 0.f;
#pragma unroll
        for (int i = 0; i < 18; ++i) {
            int li = 1024 + 2 * e + i;
            s += g18g[cg * 18 + i] * xs[li + (li >> 4)];
        }
        htail[cl][e] = s * a1d1[cg] + a1d1[32 + cg];
    }
    __syncthreads();

    // ---- hoisted x window: logical xl[16l..16l+31], conflict-free swizzle
    float xw[32];
    {
        int base = 17 * lane;
#pragma unroll
        for (int q = 0; q < 16; ++q) xw[q] = xs[base + q];
#pragma unroll
        for (int q = 0; q < 16; ++q) xw[16 + q] = xs[base + 17 + q];
    }

    for (int cc = 0; cc < 4; ++cc) {
        int cl = wv * 4 + cc;
        int cg = __builtin_amdgcn_readfirstlane(hf * 16 + cl);  // SGPR index
        float alpha = a1d1[cg], delta = a1d1[32 + cg];

        // ---- conv + BN1 + avgpool: h[8l..8l+7] in registers ----
        float hv[8];
        {
            float g[18];
#pragma unroll
            for (int i = 0; i < 18; ++i) g[i] = g18g[cg * 18 + i];
#pragma unroll
            for (int jj = 0; jj < 8; ++jj) {
                float s = 0.f;
#pragma unroll
                for (int i = 0; i < 18; ++i) s += g[i] * xw[2 * jj + i];
                hv[jj] = s * alpha + delta;
            }
        }

        // ---- stage 1: x1[4l..4l+3] / x2 (Always a1 / Eventually f1) ------
        float x1v[4], x2v[4];
        {
            float hx[14];
#pragma unroll
            for (int q = 0; q < 8; ++q) hx[q] = hv[q];
#pragma unroll
            for (int q = 0; q < 6; ++q) {
                float u = __shfl_down(hv[q], 1);
                float tl = htail[cl][q];
                hx[8 + q] = (lane == 63) ? tl : u;
            }
            float wa[8], wf[8];
            float A1 = a1b_g[cg], F1 = 1.f - f1b_g[cg];
#pragma unroll
            for (int k = 0; k < 8; ++k) {
                wa[k] = a1w_g[cg * 8 + k];
                wf[k] = f1w_g[cg * 8 + k];
                A1 -= wa[k];
            }
#pragma unroll
            for (int nn = 0; nn < 4; ++nn) {
                float s1 = A1, s2 = F1;
#pragma unroll
                for (int k = 0; k < 8; ++k) {
                    float h = hx[2 * nn + k];
                    s1 += h * wa[k];
                    s2 += h * wf[k];
                }
                x1v[nn] = s1 > 0.f ? s1 : 0.f;
                x2v[nn] = s2 > 0.f ? s2 : 0.f;
            }
        }

        // ---- stage 2: y[2l], y[2l+1] (Eventually e1 / Always fa) ---------
        float y1v[2], y2v[2];
        {
            float xx1[10], xx2[10];
#pragma unroll
            for (int q = 0; q < 4; ++q) { xx1[q] = x1v[q]; xx2[q] = x2v[q]; }
#pragma unroll
            for (int q = 0; q < 4; ++q) {
                xx1[4 + q] = __shfl_down(x1v[q], 1);
                xx2[4 + q] = __shfl_down(x2v[q], 1);
            }
#pragma unroll
            for (int q = 0; q < 2; ++q) {
                xx1[8 + q] = __shfl_down(x1v[q], 2);
                xx2[8 + q] = __shfl_down(x2v[q], 2);
            }
            float we[8], wfa[8];
            float E1 = 1.f - e1b_g[cg], FA = fab_g[cg];
#pragma unroll
            for (int k = 0; k < 8; ++k) {
                we[k]  = e1w_g[cg * 8 + k];
                wfa[k] = faw_g[cg * 8 + k];
                FA -= wfa[k];
            }
#pragma unroll
            for (int mm = 0; mm < 2; ++mm) {
                float s1 = E1, s2 = FA;
#pragma unroll
                for (int k = 0; k < 8; ++k) {
                    s1 += xx1[2 * mm + k] * we[k];
                    s2 += xx2[2 * mm + k] * wfa[k];
                }
                y1v[mm] = s1 > 0.f ? s1 : 0.f;
                y2v[mm] = s2 > 0.f ? s2 : 0.f;
            }
        }

        // ---- maxpool(4,4): lane pre-max + one static shfl ----------------
        {
            float m1 = fmaxf(y1v[0], y1v[1]);
            float m2 = fmaxf(y2v[0], y2v[1]);
            float n1 = __shfl_down(m1, 1);
            float n2 = __shfl_down(m2, 1);
            int tt = lane >> 1;
            if (!(lane & 1) && tt < L_MP) {
                int bc = b * 32 + hf * 16 + cl;
                p1[(size_t)bc * L_MP + tt] = fmaxf(m1, n1);
                p2[(size_t)bc * L_MP + tt] = fmaxf(m2, n2);
            }
        }
    }
}

// ---------------- K3b: BN2/3 stats from p1/p2 (64 blocks) -----------------
__global__ __launch_bounds__(256) void pstats_kernel(
    const float* __restrict__ p1, const float* __restrict__ p2,
    double* __restrict__ bn_d)
{
    __shared__ double wr[4][2];
    int bx = blockIdx.x, arr = bx >> 5, c = bx & 31;
    const float* p = arr ? p2 : p1;
    int t = threadIdx.x, wv = t >> 6, lane = t & 63;
    double s = 0.0, q = 0.0;
    for (int bb = t; bb < 1024; bb += 256) {
        const float* r = p + ((size_t)bb * 32 + c) * L_MP;
#pragma unroll
        for (int j = 0; j < L_MP; ++j) {
            double v = (double)r[j];
            s += v; q += v * v;
        }
    }
#pragma unroll
    for (int off = 32; off >= 1; off >>= 1) {
        s += __shfl_down(s, off);
        q += __shfl_down(q, off);
    }
    if (lane == 0) { wr[wv][0] = s; wr[wv][1] = q; }
    __syncthreads();
    if (t == 0) {
        bn_d[arr * 64 + c]      = wr[0][0] + wr[1][0] + wr[2][0] + wr[3][0];
        bn_d[arr * 64 + 32 + c] = wr[0][1] + wr[1][1] + wr[2][1] + wr[3][1];
    }
}

// ---------------- K5: BN finalize + apply + last Eventually + concat ------
__global__ __launch_bounds__(256) void final_ev_kernel(
    const float* __restrict__ p1, const float* __restrict__ p2,
    const float* __restrict__ e2w_g, const float* __restrict__ e2b_g,
    const float* __restrict__ f2w_g, const float* __restrict__ f2b_g,
    const double* __restrict__ bn_d,
    const float* __restrict__ bn2_g, const float* __restrict__ bn2_b,
    const float* __restrict__ bn3_g, const float* __restrict__ bn3_b,
    ushort* __restrict__ z0)
{
    __shared__ float pr[2][32][31];
    __shared__ float w2s[2][32][8];
    __shared__ float al[2][32], de[2][32], eb[2][32];
    int b = blockIdx.x, tid = threadIdx.x;
    for (int i = tid; i < 992; i += 256) {
        pr[0][0][i] = p1[b * 992 + i];
        pr[1][0][i] = p2[b * 992 + i];
    }
    {
        w2s[0][0][tid] = e2w_g[tid];
        w2s[1][0][tid] = f2w_g[tid];
    }
    if (tid < 64) {       // folded bn23_finalize
        int br = tid >> 5, c = tid & 31;
        double sum = bn_d[br * 64 + c], sq = bn_d[br * 64 + 32 + c];
        const double N = 1024.0 * 31.0;
        double mean = sum / N;
        double var = sq / N - mean * mean;
        float g  = br ? bn3_g[c] : bn2_g[c];
        float be = br ? bn3_b[c] : bn2_b[c];
        float alpha = g * (float)(1.0 / sqrt(var + 1e-5));
        al[br][c] = alpha;
        de[br][c] = be - (float)mean * alpha;
        eb[br][c] = br ? f2b_g[c] : e2b_g[c];
    }
    __syncthreads();
    for (int u = tid; u < 768; u += 256) {
        int br = u / 384, rem = u - br * 384;
        int c = rem / 12, tt = rem - c * 12;
        float a = al[br][c], d = de[br][c];
        float s = 1.f - eb[br][c];
#pragma unroll
        for (int k = 0; k < 8; ++k)
            s += (pr[br][c][2 * tt + k] * a + d) * w2s[br][c][k];
        z0[(size_t)b * 768 + u] = f2bf(s > 0.f ? s : 0.f);
    }
}

// ---------------- merged transpose + fp32->bf16 for all 3 weights ---------
__global__ __launch_bounds__(256) void transpose_all_kernel(
    const float* __restrict__ w1, const float* __restrict__ w2,
    const float* __restrict__ w3,
    ushort* __restrict__ wt1, ushort* __restrict__ wt2, ushort* __restrict__ wt3)
{
    __shared__ float tile[32][33];
    int bx = blockIdx.x;
    const float* W; ushort* Wt; int K, N, ntx, tl;
    if (bx < 768)       { W = w1; Wt = wt1; K = 768;  N = 1024; ntx = 32; tl = bx; }
    else if (bx < 1280) { W = w2; Wt = wt2; K = 1024; N = 512;  ntx = 16; tl = bx - 768; }
    else                { W = w3; Wt = wt3; K = 512;  N = 128;  ntx = 4;  tl = bx - 1280; }
    int n0 = (tl % ntx) * 32, k0 = (tl / ntx) * 32;
    int tx = threadIdx.x & 31, ty = threadIdx.x >> 5;
#pragma unroll
    for (int i = 0; i < 4; ++i)
        tile[ty + 8 * i][tx] = W[(size_t)(k0 + ty + 8 * i) * N + n0 + tx];
    __syncthreads();
#pragma unroll
    for (int i = 0; i < 4; ++i)
        Wt[(size_t)(n0 + ty + 8 * i) * K + k0 + tx] = f2bf(tile[tx][ty + 8 * i]);
}

// ---------------- bf16 MFMA GEMM: C = relu(A @ Bt^T + bias), bf16 out -----
// NT N-tiles per wave sharing the A fragment (loads/MFMA: NT=1 -> 2, NT=2 ->
// 1.5, with NT independent MFMA chains).
template<int NT>
__global__ __launch_bounds__(256) void gemm_mfma_kernel(
    const ushort* __restrict__ A, const ushort* __restrict__ Bt,
    const float* __restrict__ bias, ushort* __restrict__ C,
    int N, int K)
{
    int w = blockIdx.x * 4 + (threadIdx.x >> 6);
    int lane = threadIdx.x & 63;
    int nstr = N / (16 * NT);
    int mt = w / nstr, ns = w - mt * nstr;
    int r = lane & 15, q = lane >> 4;
    const ushort* ap = A + (size_t)(mt * 16 + r) * K + q * 8;
    const ushort* bp[NT];
    f4v acc[NT];
#pragma unroll
    for (int u = 0; u < NT; ++u) {
        bp[u] = Bt + (size_t)(ns * 16 * NT + u * 16 + r) * K + q * 8;
        acc[u] = (f4v){0.f, 0.f, 0.f, 0.f};
    }
    int nk = K >> 5;
    s8v a0 = *(const s8v*)ap;
    s8v b0[NT];
#pragma unroll
    for (int u = 0; u < NT; ++u) b0[u] = *(const s8v*)bp[u];
#pragma unroll 4
    for (int i = 0; i < nk; ++i) {
        int j = (i + 1 < nk) ? i + 1 : i;          // depth-1 prefetch
        s8v a1 = *(const s8v*)(ap + (size_t)j * 32);
        s8v b1[NT];
#pragma unroll
        for (int u = 0; u < NT; ++u) b1[u] = *(const s8v*)(bp[u] + (size_t)j * 32);
#pragma unroll
        for (int u = 0; u < NT; ++u)
            acc[u] = __builtin_amdgcn_mfma_f32_16x16x32_bf16(a0, b0[u], acc[u], 0, 0, 0);
        a0 = a1;
#pragma unroll
        for (int u = 0; u < NT; ++u) b0[u] = b1[u];
    }
    int row0 = mt * 16 + q * 4;
#pragma unroll
    for (int u = 0; u < NT; ++u) {
        int col = ns * 16 * NT + u * 16 + r;
        float bv = bias[col];
#pragma unroll
        for (int rr = 0; rr < 4; ++rr) {
            float v = acc[u][rr] + bv;
            v = v > 0.f ? v : 0.f;
            C[(size_t)(row0 + rr) * N + col] = f2bf(v);
        }
    }
}

// ---------------- K9: last FC (N=10), bf16 z3 in, fp32 out ----------------
__global__ __launch_bounds__(256) void fc4_kernel(
    const ushort* __restrict__ z3, const float* __restrict__ w4,
    const float* __restrict__ b4, float* __restrict__ out)
{
    int g = blockIdx.x * 256 + threadIdx.x;
    if (g >= 1024 * 10) return;
    int m = g / 10, n = g - m * 10;
    float acc = b4[n];
#pragma unroll 8
    for (int k = 0; k < 128; ++k)
        acc += bf2f(z3[m * 128 + k]) * w4[k * 10 + n];
    out[g] = acc > 0.f ? acc : 0.f;
}

// ---------------------------------------------------------------------------
extern "C" void kernel_launch(void* const* d_in, const int* in_sizes, int n_in,
                              void* d_out, int out_size, void* d_ws, size_t ws_size,
                              hipStream_t stream)
{
    (void)in_sizes; (void)n_in; (void)out_size; (void)ws_size;
    const float* x      = (const float*)d_in[0];
    const float* la_a   = (const float*)d_in[1];
    const float* la_b   = (const float*)d_in[2];
    const float* bn1_g  = (const float*)d_in[4];
    const float* bn1_b  = (const float*)d_in[5];
    const float* a1_w   = (const float*)d_in[6];
    const float* a1_b   = (const float*)d_in[7];
    const float* e1_w   = (const float*)d_in[8];
    const float* e1_b   = (const float*)d_in[9];
    const float* bn2_g  = (const float*)d_in[10];
    const float* bn2_b  = (const float*)d_in[11];
    const float* e2_w   = (const float*)d_in[12];
    const float* e2_b   = (const float*)d_in[13];
    const float* f1_w   = (const float*)d_in[14];
    const float* f1_b   = (const float*)d_in[15];
    const float* fa_w   = (const float*)d_in[16];
    const float* fa_b   = (const float*)d_in[17];
    const float* bn3_g  = (const float*)d_in[18];
    const float* bn3_b  = (const float*)d_in[19];
    const float* f2_w   = (const float*)d_in[20];
    const float* f2_b   = (const float*)d_in[21];
    const float* w1     = (const float*)d_in[22];
    const float* b1     = (const float*)d_in[23];
    const float* w2     = (const float*)d_in[24];
    const float* b2     = (const float*)d_in[25];
    const float* w3     = (const float*)d_in[26];
    const float* b3     = (const float*)d_in[27];
    const float* w4     = (const float*)d_in[28];
    const float* b4     = (const float*)d_in[29];
    float* out = (float*)d_out;

    char* w = (char*)d_ws;
    double* bn_d    = (double*)(w + 256);      // 128 dbl
    float* g18      = (float*)(w + 1536);
    float* a1d1     = (float*)(w + 3840);
    float* p1       = (float*)(w + 8192);                 // 4,063,232
    float* p2       = (float*)(w + 4071424);              // 4,063,232
    ushort* z0bf    = (ushort*)(w + 8134656);             // 1,572,864
    ushort* z1bf    = (ushort*)(w + 9707520);             // 2,097,152
    ushort* z2bf    = (ushort*)(w + 11804672);            // 1,048,576
    ushort* z3bf    = (ushort*)(w + 12853248);            // 262,144
    ushort* wt1     = (ushort*)(w + 13115392);            // 1,572,864
    ushort* wt2     = (ushort*)(w + 14688256);            // 1,048,576
    ushort* wt3     = (ushort*)(w + 15736832);            // 131,072
    double* xp      = (double*)(w + 15867904);            // 139,264 -> 16,007,168

    xstats_kernel<<<1024, 256, 0, stream>>>(x, xp);
    prep_kernel<<<1, 512, 0, stream>>>(xp, la_a, la_b, bn1_g, bn1_b, g18, a1d1);
    branches_kernel<<<2048, 256, 0, stream>>>(
        x, g18, a1d1, a1_w, a1_b, e1_w, e1_b, f1_w, f1_b, fa_w, fa_b, p1, p2);
    pstats_kernel<<<64, 256, 0, stream>>>(p1, p2, bn_d);
    final_ev_kernel<<<1024, 256, 0, stream>>>(
        p1, p2, e2_w, e2_b, f2_w, f2_b, bn_d, bn2_g, bn2_b, bn3_g, bn3_b, z0bf);
    transpose_all_kernel<<<1344, 256, 0, stream>>>(w1, w2, w3, wt1, wt2, wt3);
    // gemm1: 64 x 32 strips (NT=2) = 2048 waves; gemm2: NT=2 -> 1024 waves
    // would underfill, use NT=1 (2048 waves); gemm3: NT=1 (512 waves).
    gemm_mfma_kernel<2><<<512, 256, 0, stream>>>(z0bf, wt1, b1, z1bf, 1024, 768);
    gemm_mfma_kernel<1><<<512, 256, 0, stream>>>(z1bf, wt2, b2, z2bf, 512, 1024);
    gemm_mfma_kernel<1><<<128, 256, 0, stream>>>(z2bf, wt3, b3, z3bf, 128, 512);
    fc4_kernel<<<40, 256, 0, stream>>>(z3bf, w4, b4, out);
}

// Round 10
// 220.433 us; speedup vs baseline: 1.0752x; 1.0100x over previous
//
#include <hip/hip_runtime.h>
#include <math.h>

// ---------------------------------------------------------------------------
// Sparse_Attn_Logic — round 10.
// R9: 222.6us; profile blinded by harness's 268MB ws re-poison fills (~41us,
// fixed). All our kernels <41us; the chain is a serial 10-node graph, so the
// remaining lever is node count. This round: (a) xstats + weight-transpose
// merged into one leaf kernel (independent work, branch on blockIdx);
// (b) gemm3 + fc4 fused (z3 strip lives in LDS, never touches HBM).
// 10 -> 8 dispatches; numerics identical to R9.
// ---------------------------------------------------------------------------

#define L_MP 31

using s8v = __attribute__((ext_vector_type(8))) short;   // 8 bf16 = 4 VGPRs
using f4v = __attribute__((ext_vector_type(4))) float;   // MFMA acc

__device__ __forceinline__ ushort f2bf(float f) {        // RNE fp32->bf16
    unsigned u = __float_as_uint(f);
    u += 0x7fffu + ((u >> 16) & 1u);
    return (ushort)(u >> 16);
}
__device__ __forceinline__ float bf2f(ushort u) {
    return __uint_as_float(((unsigned)u) << 16);
}

// ---------------- K1: x-stats partials  ∪  weight transpose ---------------
// blocks [0,1024): xstats for batch row b=bx -> xp[17][1024]
// blocks [1024,2368): 32x32 transpose+bf16 tiles of w1/w2/w3 -> wt1/wt2/wt3
__global__ __launch_bounds__(256) void leaf_kernel(
    const float* __restrict__ x, double* __restrict__ xp,
    const float* __restrict__ w1, const float* __restrict__ w2,
    const float* __restrict__ w3,
    ushort* __restrict__ wt1, ushort* __restrict__ wt2, ushort* __restrict__ wt3)
{
    __shared__ __align__(16) float xr[1040];
    __shared__ float wred[4][17];
    __shared__ float tile[32][33];
    int bx = blockIdx.x, tid = threadIdx.x;

    if (bx < 1024) {
        int b = bx;
        for (int i = tid; i < 1024; i += 256) xr[i] = x[b * 1024 + i];
        if (tid < 16) xr[1024 + tid] = 0.f;
        __syncthreads();
        float acc[17];
#pragma unroll
        for (int d = 0; d < 17; ++d) acc[d] = 0.f;
        for (int p = tid; p < 1024; p += 256) {
            float v = xr[p];
            acc[16] += v;
#pragma unroll
            for (int d = 0; d < 16; ++d)
                acc[d] += v * xr[p + d];
        }
#pragma unroll
        for (int off = 32; off >= 1; off >>= 1)
#pragma unroll
            for (int d = 0; d < 17; ++d)
                acc[d] += __shfl_down(acc[d], off);
        int wave = tid >> 6, lane = tid & 63;
        if (lane == 0)
            for (int d = 0; d < 17; ++d) wred[wave][d] = acc[d];
        __syncthreads();
        if (tid < 17) {
            double tot = (double)wred[0][tid] + (double)wred[1][tid]
                       + (double)wred[2][tid] + (double)wred[3][tid];
            xp[tid * 1024 + b] = tot;
        }
    } else {
        int t2 = bx - 1024;
        const float* W; ushort* Wt; int K, N, ntx, tl;
        if (t2 < 768)       { W = w1; Wt = wt1; K = 768;  N = 1024; ntx = 32; tl = t2; }
        else if (t2 < 1280) { W = w2; Wt = wt2; K = 1024; N = 512;  ntx = 16; tl = t2 - 768; }
        else                { W = w3; Wt = wt3; K = 512;  N = 128;  ntx = 4;  tl = t2 - 1280; }
        int n0 = (tl % ntx) * 32, k0 = (tl / ntx) * 32;
        int tx = tid & 31, ty = tid >> 5;
#pragma unroll
        for (int i = 0; i < 4; ++i)
            tile[ty + 8 * i][tx] = W[(size_t)(k0 + ty + 8 * i) * N + n0 + tx];
        __syncthreads();
#pragma unroll
        for (int i = 0; i < 4; ++i)
            Wt[(size_t)(n0 + ty + 8 * i) * K + k0 + tx] = f2bf(tile[tx][ty + 8 * i]);
    }
}

// ---------------- K2: reduce xp + filters + analytic BN1 (merged) ---------
__global__ __launch_bounds__(512) void prep_kernel(
    const double* __restrict__ xp,
    const float* __restrict__ la_a, const float* __restrict__ la_b,
    const float* __restrict__ bn1_g, const float* __restrict__ bn1_b,
    float* __restrict__ g18_out, float* __restrict__ a1d1_out)
{
    __shared__ double stats[17];
    __shared__ float fs[32][16];
    int tid = threadIdx.x, wv = tid >> 6, lane = tid & 63;

    for (int row = wv; row < 17; row += 8) {
        const double* r = xp + (size_t)row * 1024;
        double a = 0.0;
        for (int i = lane; i < 1024; i += 64) a += r[i];
#pragma unroll
        for (int off = 32; off >= 1; off >>= 1) a += __shfl_down(a, off);
        if (lane == 0) stats[row] = a;
    }

    {
        int c = tid >> 4, k = tid & 15;
        const double A = 0.08, ep = 0.03, tal = 0.1;
        const double w = 2.0 * 3.14159265358979323846 * 50.0;
        const double q = 1.0 - ep * ep;
        double t = (double)k / 15.0;
        double p = t - (double)la_b[c] / (double)la_a[c];
        double arg = w * (p - tal);
        double y = A * exp(-ep / sqrt(q) * arg) * (-sin(arg));
        fs[c][k] = (float)y;
    }
    __syncthreads();
    if (tid < 32) {
        int c = tid;
        for (int i = 0; i < 18; ++i) {
            float g = 0.f;
            for (int k = i - 2; k <= i; ++k)
                if (k >= 0 && k < 16) g += fs[c][k];
            g18_out[c * 18 + i] = g;
        }
        double Sf = 0.0;
        for (int k = 0; k < 16; ++k) Sf += (double)fs[c][k];
        double E2 = 0.0;
        for (int k = 0; k < 16; ++k)
            for (int k2 = 0; k2 < 16; ++k2)
                E2 += (double)fs[c][k] * (double)fs[c][k2]
                    * stats[k > k2 ? k - k2 : k2 - k];
        const double N = 1024.0 * 1041.0;
        double Sx = stats[16];
        double mc  = Sx * Sf / N;
        double var = E2 / N - mc * mc;
        double invstd = 1.0 / sqrt(var + 1e-5);
        float alpha = bn1_g[c] * (float)invstd;
        a1d1_out[c]      = alpha / 3.0f;
        a1d1_out[32 + c] = bn1_b[c] - (float)mc * alpha;
    }
}

// ---------------- K3: fused conv+BN+pool + both branches ------------------
__global__ __launch_bounds__(256) void branches_kernel(
    const float* __restrict__ x,
    const float* __restrict__ g18g, const float* __restrict__ a1d1,
    const float* __restrict__ a1w_g, const float* __restrict__ a1b_g,
    const float* __restrict__ e1w_g, const float* __restrict__ e1b_g,
    const float* __restrict__ f1w_g, const float* __restrict__ f1b_g,
    const float* __restrict__ faw_g, const float* __restrict__ fab_g,
    float* __restrict__ p1, float* __restrict__ p2)
{
    __shared__ float xs[1140];            // swizzled x, P(i)=i+(i>>4)
    __shared__ float htail[16][6];

    int blk = blockIdx.x;
    int b = blk >> 1, hf = blk & 1;
    int t = threadIdx.x;
    int wv = t >> 6, lane = t & 63;

    {
        float4 v = ((const float4*)(x + (size_t)b * 1024))[t];
        int li = 16 + 4 * t;
        int ph = li + (li >> 4);
        xs[ph] = v.x; xs[ph + 1] = v.y; xs[ph + 2] = v.z; xs[ph + 3] = v.w;
        if (t < 16) xs[t] = 0.f;
        if (t < 32) { int i = 1040 + t; xs[i + (i >> 4)] = 0.f; }
    }
    __syncthreads();

    if (t < 96) {
        int cl = t / 6, e = t - 6 * (t / 6);
        int cg = hf * 16 + cl;
        float s = 0.f;
#pragma unroll
        for (int i = 0; i < 18; ++i) {
            int li = 1024 + 2 * e + i;
            s += g18g[cg * 18 + i] * xs[li + (li >> 4)];
        }
        htail[cl][e] = s * a1d1[cg] + a1d1[32 + cg];
    }
    __syncthreads();

    float xw[32];
    {
        int base = 17 * lane;
#pragma unroll
        for (int q = 0; q < 16; ++q) xw[q] = xs[base + q];
#pragma unroll
        for (int q = 0; q < 16; ++q) xw[16 + q] = xs[base + 17 + q];
    }

    for (int cc = 0; cc < 4; ++cc) {
        int cl = wv * 4 + cc;
        int cg = __builtin_amdgcn_readfirstlane(hf * 16 + cl);  // SGPR index
        float alpha = a1d1[cg], delta = a1d1[32 + cg];

        float hv[8];
        {
            float g[18];
#pragma unroll
            for (int i = 0; i < 18; ++i) g[i] = g18g[cg * 18 + i];
#pragma unroll
            for (int jj = 0; jj < 8; ++jj) {
                float s = 0.f;
#pragma unroll
                for (int i = 0; i < 18; ++i) s += g[i] * xw[2 * jj + i];
                hv[jj] = s * alpha + delta;
            }
        }

        float x1v[4], x2v[4];
        {
            float hx[14];
#pragma unroll
            for (int q = 0; q < 8; ++q) hx[q] = hv[q];
#pragma unroll
            for (int q = 0; q < 6; ++q) {
                float u = __shfl_down(hv[q], 1);
                float tl = htail[cl][q];
                hx[8 + q] = (lane == 63) ? tl : u;
            }
            float wa[8], wf[8];
            float A1 = a1b_g[cg], F1 = 1.f - f1b_g[cg];
#pragma unroll
            for (int k = 0; k < 8; ++k) {
                wa[k] = a1w_g[cg * 8 + k];
                wf[k] = f1w_g[cg * 8 + k];
                A1 -= wa[k];
            }
#pragma unroll
            for (int nn = 0; nn < 4; ++nn) {
                float s1 = A1, s2 = F1;
#pragma unroll
                for (int k = 0; k < 8; ++k) {
                    float h = hx[2 * nn + k];
                    s1 += h * wa[k];
                    s2 += h * wf[k];
                }
                x1v[nn] = s1 > 0.f ? s1 : 0.f;
                x2v[nn] = s2 > 0.f ? s2 : 0.f;
            }
        }

        float y1v[2], y2v[2];
        {
            float xx1[10], xx2[10];
#pragma unroll
            for (int q = 0; q < 4; ++q) { xx1[q] = x1v[q]; xx2[q] = x2v[q]; }
#pragma unroll
            for (int q = 0; q < 4; ++q) {
                xx1[4 + q] = __shfl_down(x1v[q], 1);
                xx2[4 + q] = __shfl_down(x2v[q], 1);
            }
#pragma unroll
            for (int q = 0; q < 2; ++q) {
                xx1[8 + q] = __shfl_down(x1v[q], 2);
                xx2[8 + q] = __shfl_down(x2v[q], 2);
            }
            float we[8], wfa[8];
            float E1 = 1.f - e1b_g[cg], FA = fab_g[cg];
#pragma unroll
            for (int k = 0; k < 8; ++k) {
                we[k]  = e1w_g[cg * 8 + k];
                wfa[k] = faw_g[cg * 8 + k];
                FA -= wfa[k];
            }
#pragma unroll
            for (int mm = 0; mm < 2; ++mm) {
                float s1 = E1, s2 = FA;
#pragma unroll
                for (int k = 0; k < 8; ++k) {
                    s1 += xx1[2 * mm + k] * we[k];
                    s2 += xx2[2 * mm + k] * wfa[k];
                }
                y1v[mm] = s1 > 0.f ? s1 : 0.f;
                y2v[mm] = s2 > 0.f ? s2 : 0.f;
            }
        }

        {
            float m1 = fmaxf(y1v[0], y1v[1]);
            float m2 = fmaxf(y2v[0], y2v[1]);
            float n1 = __shfl_down(m1, 1);
            float n2 = __shfl_down(m2, 1);
            int tt = lane >> 1;
            if (!(lane & 1) && tt < L_MP) {
                int bc = b * 32 + hf * 16 + cl;
                p1[(size_t)bc * L_MP + tt] = fmaxf(m1, n1);
                p2[(size_t)bc * L_MP + tt] = fmaxf(m2, n2);
            }
        }
    }
}

// ---------------- K3b: BN2/3 stats from p1/p2 (64 blocks) -----------------
__global__ __launch_bounds__(256) void pstats_kernel(
    const float* __restrict__ p1, const float* __restrict__ p2,
    double* __restrict__ bn_d)
{
    __shared__ double wr[4][2];
    int bx = blockIdx.x, arr = bx >> 5, c = bx & 31;
    const float* p = arr ? p2 : p1;
    int t = threadIdx.x, wv = t >> 6, lane = t & 63;
    double s = 0.0, q = 0.0;
    for (int bb = t; bb < 1024; bb += 256) {
        const float* r = p + ((size_t)bb * 32 + c) * L_MP;
#pragma unroll
        for (int j = 0; j < L_MP; ++j) {
            double v = (double)r[j];
            s += v; q += v * v;
        }
    }
#pragma unroll
    for (int off = 32; off >= 1; off >>= 1) {
        s += __shfl_down(s, off);
        q += __shfl_down(q, off);
    }
    if (lane == 0) { wr[wv][0] = s; wr[wv][1] = q; }
    __syncthreads();
    if (t == 0) {
        bn_d[arr * 64 + c]      = wr[0][0] + wr[1][0] + wr[2][0] + wr[3][0];
        bn_d[arr * 64 + 32 + c] = wr[0][1] + wr[1][1] + wr[2][1] + wr[3][1];
    }
}

// ---------------- K5: BN finalize + apply + last Eventually + concat ------
__global__ __launch_bounds__(256) void final_ev_kernel(
    const float* __restrict__ p1, const float* __restrict__ p2,
    const float* __restrict__ e2w_g, const float* __restrict__ e2b_g,
    const float* __restrict__ f2w_g, const float* __restrict__ f2b_g,
    const double* __restrict__ bn_d,
    const float* __restrict__ bn2_g, const float* __restrict__ bn2_b,
    const float* __restrict__ bn3_g, const float* __restrict__ bn3_b,
    ushort* __restrict__ z0)
{
    __shared__ float pr[2][32][31];
    __shared__ float w2s[2][32][8];
    __shared__ float al[2][32], de[2][32], eb[2][32];
    int b = blockIdx.x, tid = threadIdx.x;
    for (int i = tid; i < 992; i += 256) {
        pr[0][0][i] = p1[b * 992 + i];
        pr[1][0][i] = p2[b * 992 + i];
    }
    {
        w2s[0][0][tid] = e2w_g[tid];
        w2s[1][0][tid] = f2w_g[tid];
    }
    if (tid < 64) {
        int br = tid >> 5, c = tid & 31;
        double sum = bn_d[br * 64 + c], sq = bn_d[br * 64 + 32 + c];
        const double N = 1024.0 * 31.0;
        double mean = sum / N;
        double var = sq / N - mean * mean;
        float g  = br ? bn3_g[c] : bn2_g[c];
        float be = br ? bn3_b[c] : bn2_b[c];
        float alpha = g * (float)(1.0 / sqrt(var + 1e-5));
        al[br][c] = alpha;
        de[br][c] = be - (float)mean * alpha;
        eb[br][c] = br ? f2b_g[c] : e2b_g[c];
    }
    __syncthreads();
    for (int u = tid; u < 768; u += 256) {
        int br = u / 384, rem = u - br * 384;
        int c = rem / 12, tt = rem - c * 12;
        float a = al[br][c], d = de[br][c];
        float s = 1.f - eb[br][c];
#pragma unroll
        for (int k = 0; k < 8; ++k)
            s += (pr[br][c][2 * tt + k] * a + d) * w2s[br][c][k];
        z0[(size_t)b * 768 + u] = f2bf(s > 0.f ? s : 0.f);
    }
}

// ---------------- bf16 MFMA GEMM: C = relu(A @ Bt^T + bias), bf16 out -----
template<int NT>
__global__ __launch_bounds__(256) void gemm_mfma_kernel(
    const ushort* __restrict__ A, const ushort* __restrict__ Bt,
    const float* __restrict__ bias, ushort* __restrict__ C,
    int N, int K)
{
    int w = blockIdx.x * 4 + (threadIdx.x >> 6);
    int lane = threadIdx.x & 63;
    int nstr = N / (16 * NT);
    int mt = w / nstr, ns = w - mt * nstr;
    int r = lane & 15, q = lane >> 4;
    const ushort* ap = A + (size_t)(mt * 16 + r) * K + q * 8;
    const ushort* bp[NT];
    f4v acc[NT];
#pragma unroll
    for (int u = 0; u < NT; ++u) {
        bp[u] = Bt + (size_t)(ns * 16 * NT + u * 16 + r) * K + q * 8;
        acc[u] = (f4v){0.f, 0.f, 0.f, 0.f};
    }
    int nk = K >> 5;
    s8v a0 = *(const s8v*)ap;
    s8v b0[NT];
#pragma unroll
    for (int u = 0; u < NT; ++u) b0[u] = *(const s8v*)bp[u];
#pragma unroll 4
    for (int i = 0; i < nk; ++i) {
        int j = (i + 1 < nk) ? i + 1 : i;
        s8v a1 = *(const s8v*)(ap + (size_t)j * 32);
        s8v b1[NT];
#pragma unroll
        for (int u = 0; u < NT; ++u) b1[u] = *(const s8v*)(bp[u] + (size_t)j * 32);
#pragma unroll
        for (int u = 0; u < NT; ++u)
            acc[u] = __builtin_amdgcn_mfma_f32_16x16x32_bf16(a0, b0[u], acc[u], 0, 0, 0);
        a0 = a1;
#pragma unroll
        for (int u = 0; u < NT; ++u) b0[u] = b1[u];
    }
    int row0 = mt * 16 + q * 4;
#pragma unroll
    for (int u = 0; u < NT; ++u) {
        int col = ns * 16 * NT + u * 16 + r;
        float bv = bias[col];
#pragma unroll
        for (int rr = 0; rr < 4; ++rr) {
            float v = acc[u][rr] + bv;
            v = v > 0.f ? v : 0.f;
            C[(size_t)(row0 + rr) * N + col] = f2bf(v);
        }
    }
}

// ---------------- K8: gemm3 + fc4 fused -----------------------------------
// 64 blocks; block blk computes z3 rows blk*16..+15 (N=128, K=512) entirely
// in LDS (4 waves x NT=2 tiles), then out = relu(z3 @ w4 + b4) for those
// rows. strip padded 128->132 ushort to break the m*256B bank pattern.
__global__ __launch_bounds__(256) void gemm3_fc4_kernel(
    const ushort* __restrict__ A, const ushort* __restrict__ Bt,
    const float* __restrict__ bias, const float* __restrict__ w4,
    const float* __restrict__ b4, float* __restrict__ out)
{
    __shared__ ushort strip[16][132];
    const int K = 512, NCOL = 128;
    int blk = blockIdx.x;
    int wv = threadIdx.x >> 6, lane = threadIdx.x & 63;
    int r = lane & 15, q = lane >> 4;

    const ushort* ap  = A + (size_t)(blk * 16 + r) * K + q * 8;
    const ushort* bp0 = Bt + (size_t)(wv * 32 + r) * K + q * 8;
    const ushort* bp1 = Bt + (size_t)(wv * 32 + 16 + r) * K + q * 8;
    f4v acc0 = {0.f, 0.f, 0.f, 0.f}, acc1 = {0.f, 0.f, 0.f, 0.f};
    int nk = K >> 5;                                   // 16
    s8v a0 = *(const s8v*)ap;
    s8v c0 = *(const s8v*)bp0;
    s8v d0 = *(const s8v*)bp1;
#pragma unroll 4
    for (int i = 0; i < nk; ++i) {
        int j = (i + 1 < nk) ? i + 1 : i;
        s8v a1 = *(const s8v*)(ap + (size_t)j * 32);
        s8v c1 = *(const s8v*)(bp0 + (size_t)j * 32);
        s8v d1 = *(const s8v*)(bp1 + (size_t)j * 32);
        acc0 = __builtin_amdgcn_mfma_f32_16x16x32_bf16(a0, c0, acc0, 0, 0, 0);
        acc1 = __builtin_amdgcn_mfma_f32_16x16x32_bf16(a0, d0, acc1, 0, 0, 0);
        a0 = a1; c0 = c1; d0 = d1;
    }
    float bv0 = bias[wv * 32 + r], bv1 = bias[wv * 32 + 16 + r];
#pragma unroll
    for (int rr = 0; rr < 4; ++rr) {
        float v0 = acc0[rr] + bv0; v0 = v0 > 0.f ? v0 : 0.f;
        float v1 = acc1[rr] + bv1; v1 = v1 > 0.f ? v1 : 0.f;
        strip[q * 4 + rr][wv * 32 + r]      = f2bf(v0);
        strip[q * 4 + rr][wv * 32 + 16 + r] = f2bf(v1);
    }
    __syncthreads();

    int t = threadIdx.x;
    if (t < 160) {
        int m = t / 10, n = t - 10 * (t / 10);
        float a = b4[n];
#pragma unroll 8
        for (int k = 0; k < NCOL; ++k)
            a += bf2f(strip[m][k]) * w4[k * 10 + n];
        out[(size_t)(blk * 16 + m) * 10 + n] = a > 0.f ? a : 0.f;
    }
}

// ---------------------------------------------------------------------------
extern "C" void kernel_launch(void* const* d_in, const int* in_sizes, int n_in,
                              void* d_out, int out_size, void* d_ws, size_t ws_size,
                              hipStream_t stream)
{
    (void)in_sizes; (void)n_in; (void)out_size; (void)ws_size;
    const float* x      = (const float*)d_in[0];
    const float* la_a   = (const float*)d_in[1];
    const float* la_b   = (const float*)d_in[2];
    const float* bn1_g  = (const float*)d_in[4];
    const float* bn1_b  = (const float*)d_in[5];
    const float* a1_w   = (const float*)d_in[6];
    const float* a1_b   = (const float*)d_in[7];
    const float* e1_w   = (const float*)d_in[8];
    const float* e1_b   = (const float*)d_in[9];
    const float* bn2_g  = (const float*)d_in[10];
    const float* bn2_b  = (const float*)d_in[11];
    const float* e2_w   = (const float*)d_in[12];
    const float* e2_b   = (const float*)d_in[13];
    const float* f1_w   = (const float*)d_in[14];
    const float* f1_b   = (const float*)d_in[15];
    const float* fa_w   = (const float*)d_in[16];
    const float* fa_b   = (const float*)d_in[17];
    const float* bn3_g  = (const float*)d_in[18];
    const float* bn3_b  = (const float*)d_in[19];
    const float* f2_w   = (const float*)d_in[20];
    const float* f2_b   = (const float*)d_in[21];
    const float* w1     = (const float*)d_in[22];
    const float* b1     = (const float*)d_in[23];
    const float* w2     = (const float*)d_in[24];
    const float* b2     = (const float*)d_in[25];
    const float* w3     = (const float*)d_in[26];
    const float* b3     = (const float*)d_in[27];
    const float* w4     = (const float*)d_in[28];
    const float* b4     = (const float*)d_in[29];
    float* out = (float*)d_out;

    char* w = (char*)d_ws;
    double* bn_d    = (double*)(w + 256);      // 128 dbl
    float* g18      = (float*)(w + 1536);
    float* a1d1     = (float*)(w + 3840);
    float* p1       = (float*)(w + 8192);                 // 4,063,232
    float* p2       = (float*)(w + 4071424);              // 4,063,232
    ushort* z0bf    = (ushort*)(w + 8134656);             // 1,572,864
    ushort* z1bf    = (ushort*)(w + 9707520);             // 2,097,152
    ushort* z2bf    = (ushort*)(w + 11804672);            // 1,048,576
    ushort* wt1     = (ushort*)(w + 13115392);            // 1,572,864
    ushort* wt2     = (ushort*)(w + 14688256);            // 1,048,576
    ushort* wt3     = (ushort*)(w + 15736832);            // 131,072
    double* xp      = (double*)(w + 15867904);            // 139,264 -> 16,007,168

    leaf_kernel<<<2368, 256, 0, stream>>>(x, xp, w1, w2, w3, wt1, wt2, wt3);
    prep_kernel<<<1, 512, 0, stream>>>(xp, la_a, la_b, bn1_g, bn1_b, g18, a1d1);
    branches_kernel<<<2048, 256, 0, stream>>>(
        x, g18, a1d1, a1_w, a1_b, e1_w, e1_b, f1_w, f1_b, fa_w, fa_b, p1, p2);
    pstats_kernel<<<64, 256, 0, stream>>>(p1, p2, bn_d);
    final_ev_kernel<<<1024, 256, 0, stream>>>(
        p1, p2, e2_w, e2_b, f2_w, f2_b, bn_d, bn2_g, bn2_b, bn3_g, bn3_b, z0bf);
    gemm_mfma_kernel<2><<<512, 256, 0, stream>>>(z0bf, wt1, b1, z1bf, 1024, 768);
    gemm_mfma_kernel<1><<<512, 256, 0, stream>>>(z1bf, wt2, b2, z2bf, 512, 1024);
    gemm3_fc4_kernel<<<64, 256, 0, stream>>>(z2bf, wt3, b3, w4, b4, out);
}